// Round 6
// baseline (29.769 us; speedup 1.0000x reference)
//
#include <hip/hip_runtime.h>

#define NEXP 16
#define FIN 256
#define FOUT 256
#define NB 16
#define WCOL 16                 // output columns per block slice
#define NSLICE (FOUT / WCOL)    // 16 column slices per graph
#define MAT4 (FIN * FOUT / 4)   // 16384 float4 per (IN,OUT) matrix

// async global->LDS, 16B per lane, wave-uniform LDS base + lane*16
__device__ __forceinline__ void glds16(const float4* g, float4* l) {
    __builtin_amdgcn_global_load_lds(
        (const __attribute__((address_space(1))) void*)(const void*)g,
        (__attribute__((address_space(3))) void*)(void*)l, 16, 0, 0);
}

// ---------------------------------------------------------------------------
// Single fused kernel. 256 blocks x 1024 threads (16 waves, 1 block/CU).
// Block = (graph g, 16-col slice):
//   - issue async DMA staging of the graph's 128 input rows into LINEAR LDS
//     (source-swizzled: lane reads element lane^(row&7) -> bank-conflict-free
//     swizzled reads later)                                    [zero VGPRs]
//   - mix the 256x16 kernel slice into LDS (16 loads/thread, deep pipeline
//     now that no registers are held by staging)
//   - barrier (drains DMA + ds_write)
//   - GEMM: thread = (row r, ALL 16 cols, 8-way K-split); m_s4 reads are
//     wave-uniform broadcasts; 8 swizzled a-reads/thread  -> FMA-bound
//   - 8-way reduce through LDS aliased over dead in_s, + bias, store.
// XCD swizzle: the 2 slices sharing each 128B kern line sit on one XCD.
// ---------------------------------------------------------------------------
__global__ __launch_bounds__(1024) void mole_onepass_kernel(
    const float* __restrict__ inp,     // (N, IN)
    const int* __restrict__ n_node,    // (B,)
    const float* __restrict__ coeffs,  // (B, E)
    const float* __restrict__ kern,    // (E, IN, OUT)
    const float* __restrict__ bias,    // (OUT,)
    float* __restrict__ out)           // (N, OUT)
{
    __shared__ float4 smem[8192 + 1024];   // 144 KB
    float4* in_lin4 = smem;                // 128 rows x 64 f4 (swizzled contents)
    float4* m_s4 = smem + 8192;            // [i*4 + c4], 16 KB

    const int tid = threadIdx.x;
    const int bid = blockIdx.x;

    // XCD-chunked decode: xcd = bid&7 owns column slices {2*xcd, 2*xcd+1}
    const int xcd = bid & 7;
    const int jj0 = bid >> 3;               // 0..31
    const int cslice = 2 * xcd + (jj0 & 1); // column slice 0..15
    const int g = jj0 >> 1;                 // graph 0..15
    const int co4 = cslice * 4;             // float4 column offset

    // graph row range via prefix scan (ragged-safe, block-uniform scalar)
    int start = 0;
#pragma unroll
    for (int b = 0; b < NB; ++b) {
        const int nb = n_node[b];
        start += (b < g) ? nb : 0;
    }
    const int cnt = n_node[g];

    const float4* k4 = reinterpret_cast<const float4*>(kern);
    const float4* ip4 = reinterpret_cast<const float4*>(inp);
    float4* out4 = reinterpret_cast<float4*>(out);
    const float4* bias4 = reinterpret_cast<const float4*>(bias);

    const int wv = tid >> 6;       // wave id 0..15
    const int lane = tid & 63;

    for (int r0 = 0; r0 < cnt; r0 += 128) {
        const int rows = min(128, cnt - r0);

        // ---- stage input rows (async DMA on fast path, zero registers) ----
        if (rows == 128) {
#pragma unroll
            for (int it = 0; it < 8; ++it) {
                const int row = wv * 8 + it;   // wave-uniform
                glds16(ip4 + (size_t)(start + r0 + row) * 64 + (lane ^ it),
                       in_lin4 + row * 64);
            }
        } else {
            for (int w = tid; w < rows * 64; w += 1024) {
                const int row = w >> 6, jc = w & 63;
                in_lin4[row * 64 + (jc ^ (row & 7))] =
                    ip4[(size_t)(start + r0 + row) * 64 + jc];
            }
        }

        // ---- mix (first chunk only; overlaps the staging DMA) ----
        if (r0 == 0) {
            const int mi = tid >> 2;          // kern row i
            const int mc4 = tid & 3;          // f4 col within slice
            const float4* kp = k4 + (size_t)mi * (FOUT / 4) + co4 + mc4;
            float4 macc = make_float4(0.f, 0.f, 0.f, 0.f);
#pragma unroll
            for (int e = 0; e < NEXP; ++e) {
                const float4 kv = kp[(size_t)e * MAT4];
                const float c = coeffs[g * NEXP + e];
                macc.x += c * kv.x;
                macc.y += c * kv.y;
                macc.z += c * kv.z;
                macc.w += c * kv.w;
            }
            m_s4[tid] = macc;
        }
        __syncthreads();   // drains DMA (vmcnt) + m_s4 ds_write (lgkm)

        // ---- GEMM: thread = (row r, all 16 cols, K-split ks of 8) ----
        const int r = tid & 127;
        const int ks = tid >> 7;
        const int r7 = r & 7;
        float4 acc0 = make_float4(0.f, 0.f, 0.f, 0.f);
        float4 acc1 = acc0, acc2 = acc0, acc3 = acc0;

        if (r < rows) {
            const float4* arow = in_lin4 + r * 64 + ks * 8;
#pragma unroll
            for (int i4 = 0; i4 < 8; ++i4) {
                const float4 a = arow[i4 ^ r7];           // de-swizzle read
                const float4* mp = m_s4 + (ks * 8 + i4) * 16;  // wave-uniform
#pragma unroll
                for (int s = 0; s < 4; ++s) {
                    const float as = (s == 0) ? a.x : (s == 1) ? a.y
                                   : (s == 2) ? a.z : a.w;
                    const float4 m0 = mp[s * 4 + 0];
                    const float4 m1 = mp[s * 4 + 1];
                    const float4 m2 = mp[s * 4 + 2];
                    const float4 m3 = mp[s * 4 + 3];
                    acc0.x += as * m0.x; acc0.y += as * m0.y;
                    acc0.z += as * m0.z; acc0.w += as * m0.w;
                    acc1.x += as * m1.x; acc1.y += as * m1.y;
                    acc1.z += as * m1.z; acc1.w += as * m1.w;
                    acc2.x += as * m2.x; acc2.y += as * m2.y;
                    acc2.z += as * m2.z; acc2.w += as * m2.w;
                    acc3.x += as * m3.x; acc3.y += as * m3.y;
                    acc3.z += as * m3.z; acc3.w += as * m3.w;
                }
            }
        }
        __syncthreads();   // all in_lin reads done -> safe to alias

        // ---- 8-way reduce through LDS aliased over in_s ----
        float4* red4 = in_lin4;   // [c4*1024 + ks*128 + r], 64 KB
        red4[0 * 1024 + tid] = acc0;
        red4[1 * 1024 + tid] = acc1;
        red4[2 * 1024 + tid] = acc2;
        red4[3 * 1024 + tid] = acc3;
        __syncthreads();

        if (tid < 512) {
            const int rr = tid >> 2;
            const int c4 = tid & 3;
            if (rr < rows) {
                const float4 bv = bias4[co4 + c4];
                float4 t = make_float4(bv.x, bv.y, bv.z, bv.w);
#pragma unroll
                for (int kk = 0; kk < 8; ++kk) {
                    const float4 v = red4[c4 * 1024 + kk * 128 + rr];
                    t.x += v.x;
                    t.y += v.y;
                    t.z += v.z;
                    t.w += v.w;
                }
                out4[(size_t)(start + r0 + rr) * 64 + co4 + c4] = t;
            }
        }
        if (r0 + 128 < cnt) __syncthreads();  // before restaging clobbers red
    }
}

// ---------------------------------------------------------------------------
extern "C" void kernel_launch(void* const* d_in, const int* in_sizes, int n_in,
                              void* d_out, int out_size, void* d_ws, size_t ws_size,
                              hipStream_t stream) {
    const float* inputs = (const float*)d_in[0];   // (N, IN) f32
    const int* n_node = (const int*)d_in[1];       // (B,) i32
    const float* coeffs = (const float*)d_in[2];   // (B, E) f32
    const float* kern = (const float*)d_in[3];     // (E, IN, OUT) f32
    const float* bias = (const float*)d_in[4];     // (OUT,) f32
    float* outp = (float*)d_out;                   // (N, OUT) f32

    mole_onepass_kernel<<<NB * NSLICE, 1024, 0, stream>>>(
        inputs, n_node, coeffs, kern, bias, outp);
}

// Round 7
// 15.984 us; speedup vs baseline: 1.8624x; 1.8624x over previous
//
#include <hip/hip_runtime.h>

#define NEXP 16
#define FIN 256
#define FOUT 256
#define NB 16
#define WCOL 16                 // output columns per block slice
#define NSLICE (FOUT / WCOL)    // 16 column slices per graph
#define MAT4 (FIN * FOUT / 4)   // 16384 float4 per (IN,OUT) matrix
#define ROWF4 65                // in_s row stride in float4 (260 floats):
                                // 16B-aligned b128; 65%32==1 -> 16 distinct
                                // banks per wave a-read (4-lane broadcast)

// ---------------------------------------------------------------------------
// Single fused kernel (r4 structure + targeted deltas). 256 blocks x 1024
// threads (16 waves, 1 block/CU; launch_bounds(1024,4) -> 128 VGPR cap).
// Block = (graph g, 16-col slice):
//   - issue 8 input-staging loads to REGISTERS first (overlap with mix)
//   - mix 256x16 kernel slice into LDS (16 loads/thread, all in flight
//     with 128 VGPRs)
//   - drain staged rows to padded LDS, barrier
//   - GEMM: thread = (2 rows, 1 f4col, 4-way K-split): 96 LDS reads /
//     512 FMAs (was 160); m-reads 4 distinct banks, a-reads 16 banks
//   - 4-way reduce through LDS aliased over dead in_s, + bias, store
// XCD swizzle: the 2 slices sharing each kern 128B line sit on one XCD.
// ---------------------------------------------------------------------------
__global__ __launch_bounds__(1024, 4) void mole_onepass_kernel(
    const float* __restrict__ inp,     // (N, IN)
    const int* __restrict__ n_node,    // (B,)
    const float* __restrict__ coeffs,  // (B, E)
    const float* __restrict__ kern,    // (E, IN, OUT)
    const float* __restrict__ bias,    // (OUT,)
    float* __restrict__ out)           // (N, OUT)
{
    __shared__ float4 in_s4[128 * ROWF4];   // 133,120 B padded input rows
    __shared__ float4 m_s4[FIN * 4];        // 16 KB mixed slice [i*4 + c4]
    // reduce buffer (32 KB) aliases in_s4 after GEMM reads complete

    const int tid = threadIdx.x;
    const int bid = blockIdx.x;

    // XCD-chunked decode: xcd = bid&7 owns column slices {2*xcd, 2*xcd+1}
    const int xcd = bid & 7;
    const int j0 = bid >> 3;                // 0..31
    const int cslice = 2 * xcd + (j0 & 1);  // column slice 0..15
    const int g = j0 >> 1;                  // graph 0..15
    const int co4 = cslice * 4;             // float4 column offset

    // graph row range via prefix scan (ragged-safe, block-uniform scalar)
    int start = 0;
#pragma unroll
    for (int b = 0; b < NB; ++b) {
        const int nb = n_node[b];
        start += (b < g) ? nb : 0;
    }
    const int cnt = n_node[g];

    const float4* k4 = reinterpret_cast<const float4*>(kern);
    const float4* ip4 = reinterpret_cast<const float4*>(inp);
    float4* out4 = reinterpret_cast<float4*>(out);
    const float4* bias4 = reinterpret_cast<const float4*>(bias);

    // ---- mix: 16 expert loads + FMA into m_s4[tid] ----
    auto do_mix = [&]() {
        const int mi = tid >> 2;            // kern row i
        const int mc4 = tid & 3;            // f4 col within slice
        const float4* kp = k4 + (size_t)mi * (FOUT / 4) + co4 + mc4;
        float4 macc = make_float4(0.f, 0.f, 0.f, 0.f);
#pragma unroll
        for (int e = 0; e < NEXP; ++e) {
            const float4 kv = kp[(size_t)e * MAT4];
            const float c = coeffs[g * NEXP + e];
            macc.x += c * kv.x;
            macc.y += c * kv.y;
            macc.z += c * kv.z;
            macc.w += c * kv.w;
        }
        m_s4[tid] = macc;
    };

    // ---- stage one 128-row chunk into in_s4 ----
    auto do_stage = [&](int r0, int rows, bool with_mix) {
        if (rows == 128) {
            float4 st[8];
            const float4* ib = ip4 + (size_t)(start + r0) * 64;
#pragma unroll
            for (int k = 0; k < 8; ++k) st[k] = ib[tid + 1024 * k];
            if (with_mix) do_mix();
#pragma unroll
            for (int k = 0; k < 8; ++k) {
                const int jj = tid + 1024 * k;   // wave -> 1 row, consecutive f4
                in_s4[(jj >> 6) * ROWF4 + (jj & 63)] = st[k];
            }
        } else {
            if (with_mix) do_mix();
            for (int w = tid; w < rows * 64; w += 1024)
                in_s4[(w >> 6) * ROWF4 + (w & 63)] =
                    ip4[(size_t)(start + r0) * 64 + w];
        }
    };

    // ---- GEMM + reduce + store for one chunk (entered after barrier) ----
    auto do_gemm = [&](int r0, int rows) {
        const int rr = tid & 255;
        const int rp = rr >> 2;             // row 0..63 (pair with rp+64)
        const int c4 = rr & 3;              // f4 output column within slice
        const int ksI = tid >> 8;           // K-split 0..3 (wave-uniform)

        float4 acc0 = make_float4(0.f, 0.f, 0.f, 0.f);
        float4 acc1 = acc0;

        const float4* arow0 = in_s4 + rp * ROWF4 + ksI * 16;
        const float4* arow1 = arow0 + 64 * ROWF4;
        const float4* mbase = m_s4 + ksI * 256 + c4;

#pragma unroll 4
        for (int i4 = 0; i4 < 16; ++i4) {
            const float4 a0 = arow0[i4];
            const float4 a1 = arow1[i4];
            const float4* mp = mbase + i4 * 16;
            const float4 m0 = mp[0];
            const float4 m1 = mp[4];
            const float4 m2 = mp[8];
            const float4 m3 = mp[12];

            acc0.x += a0.x * m0.x + a0.y * m1.x + a0.z * m2.x + a0.w * m3.x;
            acc0.y += a0.x * m0.y + a0.y * m1.y + a0.z * m2.y + a0.w * m3.y;
            acc0.z += a0.x * m0.z + a0.y * m1.z + a0.z * m2.z + a0.w * m3.z;
            acc0.w += a0.x * m0.w + a0.y * m1.w + a0.z * m2.w + a0.w * m3.w;

            acc1.x += a1.x * m0.x + a1.y * m1.x + a1.z * m2.x + a1.w * m3.x;
            acc1.y += a1.x * m0.y + a1.y * m1.y + a1.z * m2.y + a1.w * m3.y;
            acc1.z += a1.x * m0.z + a1.y * m1.z + a1.z * m2.z + a1.w * m3.z;
            acc1.w += a1.x * m0.w + a1.y * m1.w + a1.z * m2.w + a1.w * m3.w;
        }
        __syncthreads();   // all in_s4 reads done -> safe to alias

        float4* red = in_s4;   // [(ksI*128 + row)*4 + c4], 32 KB
        red[(ksI * 128 + rp) * 4 + c4] = acc0;
        red[(ksI * 128 + rp + 64) * 4 + c4] = acc1;
        __syncthreads();

        if (tid < 512) {
            const int row = tid >> 2;
            const int c = tid & 3;
            if (row < rows) {
                const float4 bv = bias4[co4 + c];
                float4 t = make_float4(bv.x, bv.y, bv.z, bv.w);
#pragma unroll
                for (int ks = 0; ks < 4; ++ks) {
                    const float4 v = red[(ks * 128 + row) * 4 + c];
                    t.x += v.x;
                    t.y += v.y;
                    t.z += v.z;
                    t.w += v.w;
                }
                out4[(size_t)(start + r0 + row) * 64 + co4 + c] = t;
            }
        }
    };

    // ---- chunk 0 (staging overlapped with mix) ----
    if (cnt <= 0) return;
    int rows = min(128, cnt);
    do_stage(0, rows, /*with_mix=*/true);
    __syncthreads();
    do_gemm(0, rows);

    // ---- remaining chunks (only for ragged/large graphs) ----
    for (int r0 = 128; r0 < cnt; r0 += 128) {
        __syncthreads();            // reduce-reads done before restaging
        rows = min(128, cnt - r0);
        do_stage(r0, rows, /*with_mix=*/false);
        __syncthreads();
        do_gemm(r0, rows);
    }
}

// ---------------------------------------------------------------------------
extern "C" void kernel_launch(void* const* d_in, const int* in_sizes, int n_in,
                              void* d_out, int out_size, void* d_ws, size_t ws_size,
                              hipStream_t stream) {
    const float* inputs = (const float*)d_in[0];   // (N, IN) f32
    const int* n_node = (const int*)d_in[1];       // (B,) i32
    const float* coeffs = (const float*)d_in[2];   // (B, E) f32
    const float* kern = (const float*)d_in[3];     // (E, IN, OUT) f32
    const float* bias = (const float*)d_in[4];     // (OUT,) f32
    float* outp = (float*)d_out;                   // (N, OUT) f32

    mole_onepass_kernel<<<NB * NSLICE, 1024, 0, stream>>>(
        inputs, n_node, coeffs, kern, bias, outp);
}

// Round 8
// 12.638 us; speedup vs baseline: 2.3555x; 1.2647x over previous
//
#include <hip/hip_runtime.h>

typedef __attribute__((ext_vector_type(8))) short bf16x8;
typedef __attribute__((ext_vector_type(4))) float f32x4;

#define NEXP 16
#define FIN 256
#define FOUT 256
#define NB 16
#define MAT4 (FIN * FOUT / 4)   // float4 per (IN,OUT) expert matrix

// fp32 -> bf16 round-to-nearest-even (finite inputs)
__device__ __forceinline__ unsigned short f2bf(float f) {
    unsigned int u = __float_as_uint(f);
    return (unsigned short)((u + 0x7fffu + ((u >> 16) & 1u)) >> 16);
}

// ---------------------------------------------------------------------------
// Single fused kernel. 256 blocks x 1024 threads (16 waves, 1 block/CU).
// Block = (graph g, 16-col slice cs):
//   - issue 8 input-row staging loads (fp32, registers)
//   - mix the 256x16 kernel slice in fp32 (16 loads/thread), write bf16
//     TRANSPOSED tile msT[n=16][k=256] (XOR-swizzled 16B granules)
//   - drain staged rows as bf16 x-tile xs[r=128][k=256] (same swizzle)
//   - barrier -> MFMA GEMM: D = msT(A: 16n x 32k) * xT(B: 32k x 16r)
//     8 row-tiles x 2-way K-split over 16 waves, 4 mfma_f32_16x16x32_bf16
//     each; fragment = one ds_read_b128 per operand per mfma.
//   - barrier -> K-pair reduce via 8 KB LDS + bias + float4 store.
// LDS: 64 KB x-tile + 8 KB msT + 8 KB reduce = 80 KB.
// XCD swizzle: the 2 slices sharing each kern 128B line sit on one XCD.
// ---------------------------------------------------------------------------
__global__ __launch_bounds__(1024, 4) void mole_onepass_kernel(
    const float* __restrict__ inp,     // (N, IN)
    const int* __restrict__ n_node,    // (B,)
    const float* __restrict__ coeffs,  // (B, E)
    const float* __restrict__ kern,    // (E, IN, OUT)
    const float* __restrict__ bias,    // (OUT,)
    float* __restrict__ out)           // (N, OUT)
{
    __shared__ float4 smem4[5120];          // 81920 B
    char* const smem = (char*)smem4;
    char* const xs_base = smem;             // x-tile bf16 [128][512B]
    char* const ms_base = smem + 65536;     // msT  bf16 [16][512B]
    f32x4* const red = (f32x4*)(smem + 73728);  // [8][64] f32x4

    const int tid = threadIdx.x;
    const int bid = blockIdx.x;
    const int lane = tid & 63;
    const int wv = tid >> 6;

    // XCD-chunked decode: xcd = bid&7 owns column slices {2*xcd, 2*xcd+1}
    const int xcd = bid & 7;
    const int j0 = bid >> 3;                // 0..31
    const int cslice = 2 * xcd + (j0 & 1);  // column slice 0..15
    const int g = j0 >> 1;                  // graph 0..15
    const int co4 = cslice * 4;             // float4 column offset

    // graph row range via prefix scan (ragged-safe, block-uniform scalar)
    int start = 0;
#pragma unroll
    for (int b = 0; b < NB; ++b) {
        const int nb = n_node[b];
        start += (b < g) ? nb : 0;
    }
    const int cnt = n_node[g];

    const float4* k4 = reinterpret_cast<const float4*>(kern);
    const float4* ip4 = reinterpret_cast<const float4*>(inp);
    float4* out4 = reinterpret_cast<float4*>(out);
    const float4* bias4 = reinterpret_cast<const float4*>(bias);

    // MFMA decomposition (wave-uniform): row-tile tr, K-half kh
    const int tr = wv & 7;
    const int kh = wv >> 3;
    const int ln = lane & 15;
    const int lg = lane >> 4;               // 0..3

    for (int r0 = 0; r0 < cnt; r0 += 128) {
        const int rows = min(128, cnt - r0);

        // ---- issue input staging loads (guarded; zeros for missing rows) --
        float4 st[8];
        const float4* ib = ip4 + (size_t)(start + r0) * 64;
#pragma unroll
        for (int k = 0; k < 8; ++k) {
            const int row = (tid >> 6) + 16 * k;
            st[k] = (row < rows) ? ib[tid + 1024 * k]
                                 : make_float4(0.f, 0.f, 0.f, 0.f);
        }

        // ---- mix (first chunk only; fp32 exact), write bf16 msT ----------
        if (r0 == 0) {
            const int mi = tid >> 2;        // k index 0..255
            const int mc4 = tid & 3;        // f4-col within 16-wide slice
            const float4* kp = k4 + (size_t)mi * (FOUT / 4) + co4 + mc4;
            float4 macc = make_float4(0.f, 0.f, 0.f, 0.f);
#pragma unroll
            for (int e = 0; e < NEXP; ++e) {
                const float4 kv = kp[(size_t)e * MAT4];
                const float c = coeffs[g * NEXP + e];
                macc.x += c * kv.x;
                macc.y += c * kv.y;
                macc.z += c * kv.z;
                macc.w += c * kv.w;
            }
            // msT[n][k=mi], byte = n*512 + swz granule(mi>>3) + (mi&7)*2
            const float mv[4] = {macc.x, macc.y, macc.z, macc.w};
#pragma unroll
            for (int s = 0; s < 4; ++s) {
                const int n = mc4 * 4 + s;
                const int byte = n * 512 + ((((mi >> 3) ^ (n & 7)) << 4))
                               + (mi & 7) * 2;
                *reinterpret_cast<unsigned short*>(ms_base + byte) = f2bf(mv[s]);
            }
        }

        // ---- drain staged rows as bf16 x-tile (swizzled) ------------------
#pragma unroll
        for (int k = 0; k < 8; ++k) {
            const int row = (tid >> 6) + 16 * k;
            const int c4 = tid & 63;        // f4 index -> k = c4*4..+3
            ushort4 p;
            p.x = f2bf(st[k].x);
            p.y = f2bf(st[k].y);
            p.z = f2bf(st[k].z);
            p.w = f2bf(st[k].w);
            const int byte = row * 512 + ((((c4 >> 1) ^ (row & 7)) << 4))
                           + (c4 & 1) * 8;
            *reinterpret_cast<ushort4*>(xs_base + byte) = p;
        }
        __syncthreads();

        // ---- MFMA GEMM: D[n][r] = sum_k msT[n][k] * x[r][k] ---------------
        f32x4 acc = {0.f, 0.f, 0.f, 0.f};
        const int xr = tr * 16 + ln;        // local x-row for B-frag
#pragma unroll
        for (int kc8 = 0; kc8 < 4; ++kc8) {
            const int kc = kh * 4 + kc8;    // K-chunk of 32
            const int gran = kc * 4 + lg;   // 16B granule index along k
            const bf16x8 a = *reinterpret_cast<const bf16x8*>(
                ms_base + ln * 512 + ((gran ^ (ln & 7)) << 4));
            const bf16x8 b = *reinterpret_cast<const bf16x8*>(
                xs_base + xr * 512 + ((gran ^ (xr & 7)) << 4));
            acc = __builtin_amdgcn_mfma_f32_16x16x32_bf16(a, b, acc, 0, 0, 0);
        }

        if (kh == 1) red[tr * 64 + lane] = acc;
        __syncthreads();

        if (kh == 0) {
            const f32x4 p = red[tr * 64 + lane];
            const int r = tr * 16 + ln;     // local output row (= D col)
            if (r < rows) {
                const float4 bv = bias4[co4 + lg];
                float4 o;
                o.x = acc[0] + p[0] + bv.x;
                o.y = acc[1] + p[1] + bv.y;
                o.z = acc[2] + p[2] + bv.z;
                o.w = acc[3] + p[3] + bv.w;
                out4[(size_t)(start + r0 + r) * 64 + co4 + lg] = o;
            }
        }
        // next chunk's staging (global loads) + drain happen after the
        // reduce barrier; x-tile readers (MFMA) all completed before it.
    }
}

// ---------------------------------------------------------------------------
extern "C" void kernel_launch(void* const* d_in, const int* in_sizes, int n_in,
                              void* d_out, int out_size, void* d_ws, size_t ws_size,
                              hipStream_t stream) {
    const float* inputs = (const float*)d_in[0];   // (N, IN) f32
    const int* n_node = (const int*)d_in[1];       // (B,) i32
    const float* coeffs = (const float*)d_in[2];   // (B, E) f32
    const float* kern = (const float*)d_in[3];     // (E, IN, OUT) f32
    const float* bias = (const float*)d_in[4];     // (OUT,) f32
    float* outp = (float*)d_out;                   // (N, OUT) f32

    mole_onepass_kernel<<<256, 1024, 0, stream>>>(
        inputs, n_node, coeffs, kern, bias, outp);
}